// Round 5
// baseline (658.228 us; speedup 1.0000x reference)
//
#include <hip/hip_runtime.h>
#include <hip/hip_bf16.h>
#include <stdint.h>

#define B_ 32
#define S_ 2048
#define H_ 1024

typedef __attribute__((ext_vector_type(8))) short short8;
typedef __attribute__((ext_vector_type(4))) float floatx4;

__device__ inline unsigned short f32_bf16(float f) {
    union { float f; unsigned u; } v; v.f = f;
    unsigned u = v.u;
    u += 0x7fff + ((u >> 16) & 1);   // round-to-nearest-even
    return (unsigned short)(u >> 16);
}
__device__ inline unsigned pack_bf2(float a, float b) {
    return (unsigned)f32_bf16(a) | ((unsigned)f32_bf16(b) << 16);
}
__device__ inline float bf_lo(unsigned u) { union { unsigned u; float f; } v; v.u = u << 16; return v.f; }
__device__ inline float bf_hi(unsigned u) { union { unsigned u; float f; } v; v.u = u & 0xffff0000u; return v.f; }

__device__ inline float tanh_fast(float x) {
    float e = __expf(2.0f * x);
    return 1.0f - 2.0f / (e + 1.0f);
}

__device__ inline void gld16(const void* g, void* l) {
    __builtin_amdgcn_global_load_lds(
        (const __attribute__((address_space(1))) unsigned int*)g,
        (__attribute__((address_space(3))) unsigned int*)l, 16, 0, 0);
}

// ---------------- prep (small): Ua->bf16, qproj ------------------------------
#define UACVT_BLOCKS 512           // 1M elems / 2048 per block
#define QP_BLOCKS 64
__global__ void k_prep(const float* __restrict__ ua, unsigned short* __restrict__ uab,
                       const float* __restrict__ query, const float* __restrict__ Wa_w,
                       const float* __restrict__ Wa_b, const float* __restrict__ Ua_b,
                       float* __restrict__ qsum) {
    int blk = blockIdx.x, t = threadIdx.x;
    if (blk < UACVT_BLOCKS) {
        size_t base = (size_t)blk * 2048;
        float4 v0 = *(const float4*)(ua + base + t * 4);
        float4 v1 = *(const float4*)(ua + base + 1024 + t * 4);
        *(uint2*)(uab + base + t * 4)        = make_uint2(pack_bf2(v0.x, v0.y), pack_bf2(v0.z, v0.w));
        *(uint2*)(uab + base + 1024 + t * 4) = make_uint2(pack_bf2(v1.x, v1.y), pack_bf2(v1.z, v1.w));
    } else {
        // qproj: qsum[b,g] = query[b]·Wa_w[g] + Wa_b[g] + Ua_b[g]
        __shared__ float qs_l[32][68];
        int g0 = (blk - UACVT_BLOCKS) * 16;
        int r = t >> 4, l = t & 15;
        int g = g0 + r;
        float acc[32];
#pragma unroll
        for (int b = 0; b < 32; ++b) acc[b] = 0.0f;
        int sb = t >> 3, sc = (t & 7) * 8;
        for (int hc = 0; hc < 16; ++hc) {
            __syncthreads();
            float4 v0 = *(const float4*)(query + (size_t)sb * H_ + hc * 64 + sc);
            float4 v1 = *(const float4*)(query + (size_t)sb * H_ + hc * 64 + sc + 4);
            *(float4*)&qs_l[sb][sc]     = v0;
            *(float4*)&qs_l[sb][sc + 4] = v1;
            __syncthreads();
            float4 w = *(const float4*)(Wa_w + (size_t)g * H_ + hc * 64 + l * 4);
#pragma unroll
            for (int b = 0; b < 32; ++b) {
                float4 q4 = *(const float4*)&qs_l[b][l * 4];
                acc[b] += w.x * q4.x + w.y * q4.y + w.z * q4.z + w.w * q4.w;
            }
        }
#pragma unroll
        for (int b = 0; b < 32; ++b) {
            float a = acc[b];
            a += __shfl_xor(a, 1); a += __shfl_xor(a, 2);
            a += __shfl_xor(a, 4); a += __shfl_xor(a, 8);
            acc[b] = a;
        }
        if (l == 0) {
            float bias = Wa_b[g] + Ua_b[g];
#pragma unroll
            for (int b = 0; b < 32; ++b) qsum[b * H_ + g] = acc[b] + bias;
        }
    }
}

// ---------------- fused cvt + GEMM + tanh + Va reduction ---------------------
// A = keys fp32 -> bf16 in-staging (nc==0 blocks persist bf16 tile to keysbf
// for k_ctx1). C[ms,g] = sum_h keys[ms,h]*Ua[g,h]; scores_p per-nc partials.
#define BM 128
#define BN 128
#define BK 64

__global__ __launch_bounds__(256, 4) void k_scores(
    const float* __restrict__ keys, unsigned short* __restrict__ keysbf,
    const unsigned short* __restrict__ uab,
    const float* __restrict__ qsum, const float* __restrict__ va,
    float* __restrict__ scores_p)
{
    __shared__ unsigned short Al[BM * BK];   // 16 KB, [128][64], col-group swizzled
    __shared__ unsigned short Bl[BN * BK];   // 16 KB

    int bx = blockIdx.x;
    int x  = bx & 7;                   // XCD
    int i  = bx >> 3;
    int tile_m = x * 64 + (i >> 3);
    int nc     = i & 7;
    int m_base = tile_m * BM;
    int b      = m_base >> 11;
    int g0     = nc * BN;
    bool ncz   = (nc == 0);

    int tid = threadIdx.x;
    int wid = tid >> 6, lane = tid & 63;
    int wm = wid >> 1, wn = wid & 1;
    int q = lane >> 4, cn = lane & 15;

    // ---- B staging (global_load_lds): 8 rows x 8 col-groups per call, swizzled
    int rl8 = lane >> 3;               // row within call group, == row&7
    int lc8 = lane & 7;                // phys col-group
    int gcg = lc8 ^ rl8;               // fetched global col-group
    const unsigned short* pB[4];
    unsigned short* lB[4];
#pragma unroll
    for (int j = 0; j < 4; ++j) {
        int row = wid * 32 + j * 8 + rl8;
        pB[j] = uab + (size_t)(g0 + row) * H_ + gcg * 8;
        lB[j] = &Bl[(wid * 32 + j * 8) * BK];
    }
    // ---- A staging: fp32 VGPR load + pack + swizzled ds_write
    int arow[4];
    const float* pA[4];
    unsigned short* wA[4];
    unsigned short* sA[4];
#pragma unroll
    for (int j = 0; j < 4; ++j) {
        arow[j] = wid * 32 + j * 8 + rl8;
        pA[j] = keys + (size_t)(m_base + arow[j]) * H_ + lc8 * 8;
        wA[j] = &Al[arow[j] * BK + (lc8 ^ rl8) * 8];
        sA[j] = keysbf + (size_t)(m_base + arow[j]) * H_ + lc8 * 8;
    }

    // ---- fragment read offsets: row r, k-chunk kk (0/1), col = kk*32+q*8
    int aoff[2][4], boff[2][4];
#pragma unroll
    for (int kk = 0; kk < 2; ++kk)
#pragma unroll
        for (int ii = 0; ii < 4; ++ii) {
            int r  = wm * 64 + ii * 16 + cn;
            aoff[kk][ii] = r * BK + ((kk * 4 + q) ^ (r & 7)) * 8;
            int rb = wn * 64 + ii * 16 + cn;
            boff[kk][ii] = rb * BK + ((kk * 4 + q) ^ (rb & 7)) * 8;
        }

    floatx4 acc[4][4];
#pragma unroll
    for (int ii = 0; ii < 4; ++ii)
#pragma unroll
        for (int jj = 0; jj < 4; ++jj)
            acc[ii][jj] = (floatx4)(0.0f);

    for (int kc = 0; kc < H_ / BK; ++kc) {
        int ko = kc * BK;
        __syncthreads();
#pragma unroll
        for (int j = 0; j < 4; ++j)
            gld16(pB[j] + ko, lB[j]);
#pragma unroll
        for (int j = 0; j < 4; ++j) {
            float4 f4a = *(const float4*)(pA[j] + ko);
            float4 f4b = *(const float4*)(pA[j] + ko + 4);
            uint4 pk;
            pk.x = pack_bf2(f4a.x, f4a.y);
            pk.y = pack_bf2(f4a.z, f4a.w);
            pk.z = pack_bf2(f4b.x, f4b.y);
            pk.w = pack_bf2(f4b.z, f4b.w);
            *(uint4*)wA[j] = pk;
            if (ncz) *(uint4*)(sA[j] + ko) = pk;   // persist bf16 keys for ctx
        }
        __syncthreads();
#pragma unroll
        for (int kk = 0; kk < 2; ++kk) {
            short8 af[4], bf[4];
#pragma unroll
            for (int ii = 0; ii < 4; ++ii) af[ii] = *(const short8*)&Al[aoff[kk][ii]];
#pragma unroll
            for (int jj = 0; jj < 4; ++jj) bf[jj] = *(const short8*)&Bl[boff[kk][jj]];
#pragma unroll
            for (int ii = 0; ii < 4; ++ii)
#pragma unroll
                for (int jj = 0; jj < 4; ++jj)
                    acc[ii][jj] = __builtin_amdgcn_mfma_f32_16x16x32_bf16(
                        af[ii], bf[jj], acc[ii][jj], 0, 0, 0);
        }
    }

    // epilogue: scores_p partial = sum_g Va[g] * tanh(qsum[b,g] + C)
    float qs[4], vw[4];
#pragma unroll
    for (int jj = 0; jj < 4; ++jj) {
        int g = g0 + wn * 64 + jj * 16 + cn;
        qs[jj] = qsum[b * H_ + g];
        vw[jj] = va[g];
    }
    float* slab = scores_p + (size_t)nc * (B_ * S_) + b * S_;
#pragma unroll
    for (int ii = 0; ii < 4; ++ii) {
        float rs[4] = {0.f, 0.f, 0.f, 0.f};
#pragma unroll
        for (int jj = 0; jj < 4; ++jj) {
#pragma unroll
            for (int r = 0; r < 4; ++r)
                rs[r] += vw[jj] * tanh_fast(qs[jj] + acc[ii][jj][r]);
        }
#pragma unroll
        for (int r = 0; r < 4; ++r) {
            for (int mm = 1; mm < 16; mm <<= 1)
                rs[r] += __shfl_xor(rs[r], mm);
        }
        if (cn == 0) {
            int msrow = (m_base & (S_ - 1)) + wm * 64 + ii * 16 + q * 4;
            float* sp = slab + (size_t)wn * (8 * B_ * S_) + msrow;
            sp[0] = rs[0]; sp[1] = rs[1]; sp[2] = rs[2]; sp[3] = rs[3];
        }
    }
}

// ---------------- softmax over S per batch (reduces 16 partial slabs) --------
__global__ void k_softmax(const float* __restrict__ scores_p, float* __restrict__ weights) {
    int b = blockIdx.x;
    int t = threadIdx.x;
    __shared__ float red[4];
    float v[8];
    float mx = -1e30f;
#pragma unroll
    for (int k = 0; k < 8; ++k) {
        int idx = b * S_ + t + k * 256;
        float s = 0.0f;
#pragma unroll
        for (int p = 0; p < 16; ++p) s += scores_p[(size_t)p * (B_ * S_) + idx];
        v[k] = s; mx = fmaxf(mx, s);
    }
    for (int mm = 1; mm < 64; mm <<= 1) mx = fmaxf(mx, __shfl_xor(mx, mm));
    if ((t & 63) == 0) red[t >> 6] = mx;
    __syncthreads();
    mx = fmaxf(fmaxf(red[0], red[1]), fmaxf(red[2], red[3]));
    float sum = 0.0f;
#pragma unroll
    for (int k = 0; k < 8; ++k) { v[k] = __expf(v[k] - mx); sum += v[k]; }
    for (int mm = 1; mm < 64; mm <<= 1) sum += __shfl_xor(sum, mm);
    __syncthreads();
    if ((t & 63) == 0) red[t >> 6] = sum;
    __syncthreads();
    sum = red[0] + red[1] + red[2] + red[3];
    float inv = 1.0f / sum;
#pragma unroll
    for (int k = 0; k < 8; ++k) weights[b * S_ + t + k * 256] = v[k] * inv;
}

// ---------------- context stage 1: partial[b*64+sc*2+rp][h] ------------------
__global__ void k_ctx1(const unsigned short* __restrict__ keysbf,
                       const float* __restrict__ weights, float* __restrict__ partial) {
    int blk = blockIdx.x;          // 32 b x 32 s-chunks (64 rows each)
    int b = blk >> 5, sc = blk & 31;
    int t = threadIdx.x;
    __shared__ float wl[64];
    if (t < 64) wl[t] = weights[b * S_ + sc * 64 + t];
    __syncthreads();
    const uint4* kp = (const uint4*)(keysbf + (size_t)(b * S_ + sc * 64) * H_);
    int col = t & 127;             // uint4 col (8 bf16)
    int rp  = t >> 7;              // row parity 0/1
    float a0=0,a1=0,a2=0,a3=0,a4=0,a5=0,a6=0,a7=0;
#pragma unroll 8
    for (int s = rp; s < 64; s += 2) {
        uint4 v = kp[(size_t)s * 128 + col];
        float w = wl[s];
        a0 += w * bf_lo(v.x); a1 += w * bf_hi(v.x);
        a2 += w * bf_lo(v.y); a3 += w * bf_hi(v.y);
        a4 += w * bf_lo(v.z); a5 += w * bf_hi(v.z);
        a6 += w * bf_lo(v.w); a7 += w * bf_hi(v.w);
    }
    float* pp = partial + (size_t)(b * 64 + sc * 2 + rp) * H_ + col * 8;
    float4 o0 = {a0, a1, a2, a3}, o1 = {a4, a5, a6, a7};
    *(float4*)pp = o0;
    *(float4*)(pp + 4) = o1;
}

// ---------------- context stage 2: reduce 64 partials ------------------------
__global__ void k_ctx2(const float* __restrict__ partial, float* __restrict__ ctx) {
    int b = blockIdx.x;
    int t = threadIdx.x;
    float4 a = {0.f, 0.f, 0.f, 0.f};
#pragma unroll 8
    for (int j = 0; j < 64; ++j) {
        float4 p = *(const float4*)(partial + (size_t)(b * 64 + j) * H_ + t * 4);
        a.x += p.x; a.y += p.y; a.z += p.z; a.w += p.w;
    }
    *(float4*)(ctx + b * H_ + t * 4) = a;
}

// -----------------------------------------------------------------------------
extern "C" void kernel_launch(void* const* d_in, const int* in_sizes, int n_in,
                              void* d_out, int out_size, void* d_ws, size_t ws_size,
                              hipStream_t stream) {
    const float* query = (const float*)d_in[0];
    const float* keys  = (const float*)d_in[1];
    const float* Wa_w  = (const float*)d_in[2];
    const float* Wa_b  = (const float*)d_in[3];
    const float* Ua_w  = (const float*)d_in[4];
    const float* Ua_b  = (const float*)d_in[5];
    const float* Va_w  = (const float*)d_in[6];
    // Va_b unused: softmax shift-invariant, scores not an output.

    float* out     = (float*)d_out;
    float* ctx     = out;              // [32,1,1024]
    float* weights = out + B_ * H_;    // [32,2048]

    char* ws = (char*)d_ws;
    unsigned short* keysbf  = (unsigned short*)ws;                          // 128 MB
    unsigned short* uab     = (unsigned short*)(ws + 134217728);            // 2 MB
    float*          qsum    = (float*)(ws + 134217728 + 2097152);           // 128 KB
    float*          scores_p= (float*)(ws + 134217728 + 2097152 + 131072);  // 16 slabs x 256 KB = 4 MB
    float*          partial = (float*)(ws + 134217728 + 2097152 + 131072 + 4194304); // 8 MB

    k_prep   <<<UACVT_BLOCKS + QP_BLOCKS, 256, 0, stream>>>(
        Ua_w, uab, query, Wa_w, Wa_b, Ua_b, qsum);
    k_scores <<<4096, 256, 0, stream>>>(keys, keysbf, uab, qsum, Va_w, scores_p);
    k_softmax<<<B_, 256, 0, stream>>>(scores_p, weights);
    k_ctx1   <<<B_ * 32, 256, 0, stream>>>(keysbf, weights, partial);
    k_ctx2   <<<B_, 256, 0, stream>>>(partial, ctx);
}